// Round 3
// baseline (714.647 us; speedup 1.0000x reference)
//
#include <hip/hip_runtime.h>

#define BATCH 4
#define NPTS  4096
#define KNN   16
#define DP    64
#define DM    128
#define SLD   136   // bf16 scratch row stride (272 B: 16B-aligned, non-pow2)
#define PT_SCALE 0.08838834764831845f   // 1/sqrt(128)

typedef short bf16x8 __attribute__((ext_vector_type(8)));
typedef float f32x4 __attribute__((ext_vector_type(4)));

__device__ __forceinline__ unsigned short f2b(float f) {  // f32 -> bf16 RNE
  unsigned u = __float_as_uint(f);
  return (unsigned short)((u + 0x7FFFu + ((u >> 16) & 1u)) >> 16);
}
__device__ __forceinline__ float b2f(unsigned short u) {
  return __uint_as_float(((unsigned)u) << 16);
}

// ---------------------------------------------------------------------------
// K1: exact KNN, one wave per query, pure-VALU per-lane top-16.
// Lane l scans candidates j = i*64+l keeping a private sorted 16-list of
// u64 keys (d2bits<<32|j) in registers (branchless shift-insert).
// Wave-global filter tau = min over lanes of kk[15].d2 (stale-safe upper
// bound on the global 16th distance) skips the insert body when no lane
// can possibly contribute. Final: 16 rounds of wave-min-u64 + owner pop.
// d2 uses explicit rn ops to match numpy bit-exactly; u64 keys keep the
// reference's stable tie-break by index.
// ---------------------------------------------------------------------------
__global__ __launch_bounds__(256) void knn_kernel(const float* __restrict__ xyz,
                                                  int* __restrict__ idx_out) {
  const int wv = threadIdx.x >> 6, lane = threadIdx.x & 63;
  const int qid = blockIdx.x * 4 + wv;
  const int b = qid >> 12, n = qid & 4095;
  const float* xb = xyz + (size_t)b * NPTS * 3;
  const float qx = xb[n * 3 + 0], qy = xb[n * 3 + 1], qz = xb[n * 3 + 2];

  unsigned long long kk[16];
#pragma unroll
  for (int s = 0; s < 16; ++s) kk[s] = 0xFFFFFFFFFFFFFFFFULL;
  unsigned tau = 0xFFFFFFFFu;

  for (int i = 0; i < 64; ++i) {
    const int j = i * 64 + lane;
    const float cx = xb[j * 3 + 0], cy = xb[j * 3 + 1], cz = xb[j * 3 + 2];
    const float dx = __fsub_rn(qx, cx);
    const float dy = __fsub_rn(qy, cy);
    const float dz = __fsub_rn(qz, cz);
    const float d2 =
        __fadd_rn(__fadd_rn(__fmul_rn(dx, dx), __fmul_rn(dy, dy)), __fmul_rn(dz, dz));
    const unsigned d2u = __float_as_uint(d2);
    if (__any(d2u <= tau)) {
      const unsigned long long key = ((unsigned long long)d2u << 32) | (unsigned int)j;
      bool lt[16];
#pragma unroll
      for (int s = 0; s < 16; ++s) lt[s] = key < kk[s];
#pragma unroll
      for (int s = 15; s >= 1; --s) kk[s] = lt[s] ? (lt[s - 1] ? kk[s - 1] : key) : kk[s];
      kk[0] = lt[0] ? key : kk[0];
    }
    if ((i & 3) == 3) {  // refresh wave-global threshold (butterfly min, u32)
      unsigned t = (unsigned)(kk[15] >> 32);
#pragma unroll
      for (int d = 32; d >= 1; d >>= 1) {
        const unsigned o = __shfl_xor(t, d, 64);
        t = o < t ? o : t;
      }
      tau = t;
    }
  }

  // merge 64 sorted lists -> global top-16 (ascending)
  unsigned long long head = kk[0];
  unsigned long long res = 0;
  for (int r = 0; r < 16; ++r) {
    unsigned long long m = head;
#pragma unroll
    for (int d = 32; d >= 1; d >>= 1) {
      const unsigned long long o = __shfl_xor(m, d, 64);
      m = o < m ? o : m;
    }
    if (lane == r) res = m;
    if (head == m) {  // unique owner (keys unique); pop its head
#pragma unroll
      for (int s = 0; s < 15; ++s) kk[s] = kk[s + 1];
      kk[15] = 0xFFFFFFFFFFFFFFFFULL;
      head = kk[0];
    }
  }
  if (lane < 16)
    idx_out[(size_t)qid * KNN + lane] = (int)(res & 0xFFFFFFFFULL);
}

// ---------------------------------------------------------------------------
// K2: pack d2/g1/g2 weights (f32 [128][128], k-major) into bf16 MFMA
// B-fragment order: pk[((nt*4+ks)*64 + lane)*8 + i] = W[(lane>>4)*8+i+32*ks][nt*16+(lane&15)]
// ---------------------------------------------------------------------------
__global__ __launch_bounds__(256) void prep_kernel(const float* __restrict__ d2_w,
                                                   const float* __restrict__ g1_w,
                                                   const float* __restrict__ g2_w,
                                                   unsigned short* __restrict__ pk) {
  const float* W = blockIdx.x == 0 ? d2_w : (blockIdx.x == 1 ? g1_w : g2_w);
  unsigned short* o = pk + (size_t)blockIdx.x * 16384;
  for (int e = threadIdx.x; e < 16384; e += 256) {
    const int i = e & 7, l = (e >> 3) & 63, fr = e >> 9;
    const int nt = fr >> 2, ks = fr & 3;
    const int k = (l >> 4) * 8 + i + 32 * ks;
    const int c = nt * 16 + (l & 15);
    o[e] = f2b(W[k * DM + c]);
  }
}

// ---------------------------------------------------------------------------
// K3: x = features@fc1+b ; q/k/v = x@W -> stored bf16
// ---------------------------------------------------------------------------
__global__ __launch_bounds__(256) void qkv_kernel(
    const float* __restrict__ features,
    const float* __restrict__ fc1_w, const float* __restrict__ fc1_b,
    const float* __restrict__ wq, const float* __restrict__ wk, const float* __restrict__ wv,
    unsigned short* __restrict__ q_full, unsigned short* __restrict__ k_full,
    unsigned short* __restrict__ v_full) {
  __shared__ float feat_s[16][DP];
  __shared__ float x_s[16][DM];
  const size_t row0 = (size_t)blockIdx.x * 16;

  for (int i = threadIdx.x; i < 16 * DP; i += 256)
    feat_s[i >> 6][i & 63] = features[row0 * DP + i];
  __syncthreads();

  const int col = threadIdx.x & 127;
  const int rg  = (threadIdx.x >> 7) * 8;
  {
    float acc[8];
    const float bias = fc1_b[col];
#pragma unroll
    for (int r = 0; r < 8; ++r) acc[r] = bias;
    for (int k = 0; k < DP; ++k) {
      const float w = fc1_w[k * DM + col];
#pragma unroll
      for (int r = 0; r < 8; ++r) acc[r] = fmaf(feat_s[rg + r][k], w, acc[r]);
    }
#pragma unroll
    for (int r = 0; r < 8; ++r) x_s[rg + r][col] = acc[r];
  }
  __syncthreads();

  const float* Ws[3] = {wq, wk, wv};
  unsigned short* Os[3] = {q_full, k_full, v_full};
#pragma unroll
  for (int m = 0; m < 3; ++m) {
    const float* W = Ws[m];
    float acc[8];
#pragma unroll
    for (int r = 0; r < 8; ++r) acc[r] = 0.f;
    for (int k = 0; k < DM; ++k) {
      const float w = W[k * DM + col];
#pragma unroll
      for (int r = 0; r < 8; ++r) acc[r] = fmaf(x_s[rg + r][k], w, acc[r]);
    }
    unsigned short* O = Os[m] + row0 * DM;
#pragma unroll
    for (int r = 0; r < 8; ++r) O[(rg + r) * DM + col] = f2b(acc[r]);
  }
}

// ---------------------------------------------------------------------------
// K4: fused posenc + gamma + softmax + aggregation. 8 waves/block, 4 queries
// per wave. LDS ~70 KB (g1 staged bf16, per-wave bf16 scratch) -> 2 blocks/CU.
// g2 + d2 B-fragments streamed from global (L2-hot, coalesced 16B/lane).
// Scratch holds bf16 (values feed bf16 MFMA A-frags anyway).
// ---------------------------------------------------------------------------
__global__ __launch_bounds__(512, 3) void fused_attn_kernel(
    const float* __restrict__ xyz, const int* __restrict__ idxg,
    const unsigned short* __restrict__ qf, const unsigned short* __restrict__ kf,
    const unsigned short* __restrict__ vf,
    const unsigned short* __restrict__ d2pk, const unsigned short* __restrict__ g1pk,
    const unsigned short* __restrict__ g2pk,
    const float* __restrict__ d1_w, const float* __restrict__ d1_b,
    const float* __restrict__ d2_b, const float* __restrict__ g1_b,
    const float* __restrict__ g2_b,
    float* __restrict__ attn_out, float* __restrict__ res_ws) {
  __shared__ unsigned short g1s[16384];          // 32 KB
  __shared__ unsigned short sc[8][16 * SLD];     // 34 KB, per-wave bf16 scratch
  __shared__ float d1s[3 * DM];
  __shared__ float d1bs[DM], d2bs[DM], g1bs[DM], g2bs[DM];

  for (int i = threadIdx.x; i < 2048; i += 512)
    ((uint4*)g1s)[i] = ((const uint4*)g1pk)[i];
  if (threadIdx.x < 384) d1s[threadIdx.x] = d1_w[threadIdx.x];
  if (threadIdx.x < DM) {
    d1bs[threadIdx.x] = d1_b[threadIdx.x];
    d2bs[threadIdx.x] = d2_b[threadIdx.x];
    g1bs[threadIdx.x] = g1_b[threadIdx.x];
    g2bs[threadIdx.x] = g2_b[threadIdx.x];
  }
  __syncthreads();

  const int wv = threadIdx.x >> 6, lane = threadIdx.x & 63;
  const int g = lane >> 4, c15 = lane & 15;
  unsigned short* S = sc[wv];

  for (int qi = 0; qi < 4; ++qi) {
    const int qid = (blockIdx.x * 8 + wv) * 4 + qi;
    const int b = qid >> 12, n = qid & 4095;
    const size_t bN = (size_t)b * NPTS;

    // neighbor indices: lane c15 holds idx[c15]; rows for gathers via shfl
    const int myidx = idxg[(size_t)qid * KNN + c15];
    int srow[4];
#pragma unroll
    for (int i = 0; i < 4; ++i) srow[i] = __shfl(myidx, 4 * g + i, 64);

    // q row (bf16, 8 regs)
    unsigned short qred[8];
    const unsigned short* qr = qf + (size_t)qid * DM;
#pragma unroll
    for (int nt = 0; nt < 8; ++nt) qred[nt] = qr[nt * 16 + c15];

    // rel (lane's neighbor = row c15) + t1 A-frags in-register
    const float* xq = xyz + (bN + n) * 3;
    const float* xn = xyz + (bN + myidx) * 3;
    const float rx = xq[0] - xn[0], ry = xq[1] - xn[1], rz = xq[2] - xn[2];
    bf16x8 a[4];
#pragma unroll
    for (int ks = 0; ks < 4; ++ks) {
#pragma unroll
      for (int i = 0; i < 8; ++i) {
        const int cc = g * 8 + i + 32 * ks;
        float t = fmaf(rx, d1s[cc], fmaf(ry, d1s[DM + cc], fmaf(rz, d1s[2 * DM + cc], d1bs[cc])));
        a[ks][i] = (short)f2b(t > 0.f ? t : 0.f);
      }
    }
    // pos = t1@d2 + b   (B streamed from global, L2-hot)
    f32x4 pos[8];
#pragma unroll
    for (int nt = 0; nt < 8; ++nt) {
      const float bb = d2bs[nt * 16 + c15];
      f32x4 acc = {bb, bb, bb, bb};
#pragma unroll
      for (int ks = 0; ks < 4; ++ks) {
        const bf16x8 bfr = *(const bf16x8*)(d2pk + (((nt * 4 + ks) * 64 + lane) << 3));
        acc = __builtin_amdgcn_mfma_f32_16x16x32_bf16(a[ks], bfr, acc, 0, 0, 0);
      }
      pos[nt] = acc;
    }
    // h = q - k + pos -> scratch bf16 (k gathered at use; no long-lived regs)
#pragma unroll
    for (int i = 0; i < 4; ++i) {
      const unsigned short* kr = kf + (bN + srow[i]) * DM;
#pragma unroll
      for (int nt = 0; nt < 8; ++nt) {
        const float hv = b2f(qred[nt]) - b2f(kr[nt * 16 + c15]) + pos[nt][i];
        S[(4 * g + i) * SLD + nt * 16 + c15] = f2b(hv);
      }
    }
    // issue v gathers (consumed after g1/g2 -> latency hidden)
    unsigned short vred[8][4];
#pragma unroll
    for (int i = 0; i < 4; ++i) {
      const unsigned short* vr = vf + (bN + srow[i]) * DM;
#pragma unroll
      for (int nt = 0; nt < 8; ++nt) vred[nt][i] = vr[nt * 16 + c15];
    }
    // g1: A-frags straight from bf16 scratch (b128 reads)
#pragma unroll
    for (int ks = 0; ks < 4; ++ks)
      a[ks] = *(const bf16x8*)&S[c15 * SLD + g * 8 + 32 * ks];
#pragma unroll
    for (int nt = 0; nt < 8; ++nt) {
      const float bb = g1bs[nt * 16 + c15];
      f32x4 acc = {bb, bb, bb, bb};
#pragma unroll
      for (int ks = 0; ks < 4; ++ks) {
        const bf16x8 bfr = *(const bf16x8*)&g1s[((nt * 4 + ks) * 64 + lane) << 3];
        acc = __builtin_amdgcn_mfma_f32_16x16x32_bf16(a[ks], bfr, acc, 0, 0, 0);
      }
#pragma unroll
      for (int i = 0; i < 4; ++i)
        S[(4 * g + i) * SLD + nt * 16 + c15] = f2b(acc[i] > 0.f ? acc[i] : 0.f);
    }
    // g2: logits (B streamed from global)
#pragma unroll
    for (int ks = 0; ks < 4; ++ks)
      a[ks] = *(const bf16x8*)&S[c15 * SLD + g * 8 + 32 * ks];
    f32x4 lg[8];
#pragma unroll
    for (int nt = 0; nt < 8; ++nt) {
      const float bb = g2bs[nt * 16 + c15];
      f32x4 acc = {bb, bb, bb, bb};
#pragma unroll
      for (int ks = 0; ks < 4; ++ks) {
        const bf16x8 bfr = *(const bf16x8*)(g2pk + (((nt * 4 + ks) * 64 + lane) << 3));
        acc = __builtin_amdgcn_mfma_f32_16x16x32_bf16(a[ks], bfr, acc, 0, 0, 0);
      }
      lg[nt] = acc;
    }
    // softmax over K (4 in-lane vals x lane groups ^16,^32)
#pragma unroll
    for (int nt = 0; nt < 8; ++nt) {
      float s0 = lg[nt][0] * PT_SCALE, s1 = lg[nt][1] * PT_SCALE;
      float s2 = lg[nt][2] * PT_SCALE, s3 = lg[nt][3] * PT_SCALE;
      float mx = fmaxf(fmaxf(s0, s1), fmaxf(s2, s3));
      mx = fmaxf(mx, __shfl_xor(mx, 16, 64));
      mx = fmaxf(mx, __shfl_xor(mx, 32, 64));
      const float e0 = __expf(s0 - mx), e1 = __expf(s1 - mx);
      const float e2 = __expf(s2 - mx), e3 = __expf(s3 - mx);
      float sm = e0 + e1 + e2 + e3;
      sm += __shfl_xor(sm, 16, 64);
      sm += __shfl_xor(sm, 32, 64);
      const float inv = 1.f / sm;
      lg[nt][0] = e0 * inv; lg[nt][1] = e1 * inv;
      lg[nt][2] = e2 * inv; lg[nt][3] = e3 * inv;
    }
    // attn store + res = sum_k attn*(v+pos)
    float* ab = attn_out + (size_t)qid * (KNN * DM);
    float red[8];
#pragma unroll
    for (int nt = 0; nt < 8; ++nt) {
      float r4 = 0.f;
#pragma unroll
      for (int i = 0; i < 4; ++i) {
        const float pp = lg[nt][i];
        ab[(4 * g + i) * DM + nt * 16 + c15] = pp;
        r4 = fmaf(pp, b2f(vred[nt][i]) + pos[nt][i], r4);
      }
      r4 += __shfl_xor(r4, 16, 64);
      r4 += __shfl_xor(r4, 32, 64);
      red[nt] = r4;
    }
    if (g == 0) {
      float* rw = res_ws + (size_t)qid * DM;
#pragma unroll
      for (int nt = 0; nt < 8; ++nt) rw[nt * 16 + c15] = red[nt];
    }
  }
}

// ---------------------------------------------------------------------------
// K5: out = res@fc2 + fc2_b + features   (f32, 268 MFLOP, trivial)
// ---------------------------------------------------------------------------
__global__ __launch_bounds__(256) void out_kernel(
    const float* __restrict__ res, const float* __restrict__ fc2_w,
    const float* __restrict__ fc2_b, const float* __restrict__ feat,
    float* __restrict__ out) {
  __shared__ float rs[16][DM];
  const size_t row0 = (size_t)blockIdx.x * 16;
  for (int i = threadIdx.x; i < 16 * DM; i += 256)
    rs[i >> 7][i & 127] = res[row0 * DM + i];
  __syncthreads();
  const int col = threadIdx.x & 63;
  const int rg  = (threadIdx.x >> 6) * 4;
  float acc[4];
  const float bb = fc2_b[col];
#pragma unroll
  for (int r = 0; r < 4; ++r) acc[r] = bb + feat[(row0 + rg + r) * DP + col];
  for (int k = 0; k < DM; ++k) {
    const float w = fc2_w[k * DP + col];
#pragma unroll
    for (int r = 0; r < 4; ++r) acc[r] = fmaf(rs[rg + r][k], w, acc[r]);
  }
#pragma unroll
  for (int r = 0; r < 4; ++r) out[(row0 + rg + r) * DP + col] = acc[r];
}

// ---------------------------------------------------------------------------
extern "C" void kernel_launch(void* const* d_in, const int* in_sizes, int n_in,
                              void* d_out, int out_size, void* d_ws, size_t ws_size,
                              hipStream_t stream) {
  (void)in_sizes; (void)n_in; (void)out_size; (void)ws_size;
  const float* xyz      = (const float*)d_in[0];
  const float* features = (const float*)d_in[1];
  const float* fc1_w = (const float*)d_in[2];
  const float* fc1_b = (const float*)d_in[3];
  const float* fc2_w = (const float*)d_in[4];
  const float* fc2_b = (const float*)d_in[5];
  const float* d1_w  = (const float*)d_in[6];
  const float* d1_b  = (const float*)d_in[7];
  const float* d2_w  = (const float*)d_in[8];
  const float* d2_b  = (const float*)d_in[9];
  const float* g1_w  = (const float*)d_in[10];
  const float* g1_b  = (const float*)d_in[11];
  const float* g2_w  = (const float*)d_in[12];
  const float* g2_b  = (const float*)d_in[13];
  const float* wq_w  = (const float*)d_in[14];
  const float* wk_w  = (const float*)d_in[15];
  const float* wv_w  = (const float*)d_in[16];

  float* out  = (float*)d_out;
  float* attn = out + (size_t)BATCH * NPTS * DP;

  char* ws = (char*)d_ws;
  int*            idx_ws = (int*)ws;                             // 1 MB
  unsigned short* q_full = (unsigned short*)(ws + (1u << 20));   // 4 MB each
  unsigned short* k_full = (unsigned short*)(ws + (5u << 20));
  unsigned short* v_full = (unsigned short*)(ws + (9u << 20));
  float*          res_ws = (float*)(ws + (13u << 20));           // 8 MB
  unsigned short* pk     = (unsigned short*)(ws + (21u << 20));  // 96 KB

  prep_kernel<<<dim3(3), 256, 0, stream>>>(d2_w, g1_w, g2_w, pk);
  knn_kernel<<<dim3(4096), 256, 0, stream>>>(xyz, idx_ws);
  qkv_kernel<<<dim3(1024), 256, 0, stream>>>(features, fc1_w, fc1_b,
                                             wq_w, wk_w, wv_w,
                                             q_full, k_full, v_full);
  fused_attn_kernel<<<dim3(512), 512, 0, stream>>>(
      xyz, idx_ws, q_full, k_full, v_full, pk, pk + 16384, pk + 32768,
      d1_w, d1_b, d2_b, g1_b, g2_b, attn, res_ws);
  out_kernel<<<dim3(1024), 256, 0, stream>>>(res_ws, fc2_w, fc2_b, features, out);
}